// Round 14
// baseline (145.085 us; speedup 1.0000x reference)
//
#include <hip/hip_runtime.h>
#include <stdint.h>

// DeformationGraph R14: R13 (136us) + ONE change: __launch_bounds__(256,2).
//  Theory: R13's VGPR_Count=64 (compiler's 8-wave occupancy step) forces
//  acc into AGPRs (v_accvgpr_read per slot) + heavy live-range splitting
//  (~2.5x instr bloat vs static model). Grid = 1024 = exactly 4 blocks/CU,
//  so residency is GRID-limited at 4 waves/SIMD regardless of VGPR <= 128:
//  raising the cap is occupancy-free. Everything else identical to R13.

#define NPTS   65536
#define NNODES 4096
#define KSEL   20
#define CAP    32
#define BT     256
#define AFRAG_BYTES  (NNODES * 64)
#define WS_NEEDED    AFRAG_BYTES

typedef __attribute__((ext_vector_type(8)))  short short8;
typedef __attribute__((ext_vector_type(16))) float f32x16;

__device__ __forceinline__ uint32_t umin32(uint32_t a, uint32_t b) { return a < b ? a : b; }
__device__ __forceinline__ uint32_t umax32(uint32_t a, uint32_t b) { return a > b ? a : b; }
__device__ __forceinline__ void cmpswap(uint32_t& a, uint32_t& b) {
  const uint32_t lo = umin32(a, b), hi = umax32(a, b); a = lo; b = hi;
}
// bitonic MERGE network: sorts a 32-length BITONIC sequence ascending.
__device__ __forceinline__ void sort32(uint32_t arr[32]) {
#pragma unroll
  for (int dd = 16; dd >= 1; dd >>= 1)
#pragma unroll
    for (int k = 0; k < 32; ++k)
      if ((k & dd) == 0) cmpswap(arr[k], arr[k | dd]);
}
// full Batcher bitonic SORT network: sorts an ARBITRARY 32-seq ascending.
__device__ __forceinline__ void bsort32(uint32_t a[32]) {
#pragma unroll
  for (int k = 2; k <= 32; k <<= 1) {
#pragma unroll
    for (int j = k >> 1; j > 0; j >>= 1) {
#pragma unroll
      for (int i = 0; i < 32; ++i) {
        const int l = i ^ j;
        if (l > i) {
          if ((i & k) == 0) cmpswap(a[i], a[l]);   // ascending block
          else              cmpswap(a[l], a[i]);   // descending block
        }
      }
    }
  }
}
__device__ __forceinline__ void insert20(uint32_t m[KSEL], uint32_t x) {
#pragma unroll
  for (int k = KSEL - 1; k >= 1; --k)
    m[k] = umin32(m[k], umax32(m[k - 1], x));
  m[0] = umin32(m[0], x);
}
__device__ __forceinline__ float thr_from(uint32_t m19) {
  return __uint_as_float(umin32((m19 >> 12) << 11, 0x7F7FFFFFu));
}
__device__ __forceinline__ unsigned short f2bf(float x) {   // RNE fp32->bf16
  uint32_t u = __float_as_uint(x);
  return (unsigned short)((u + 0x7FFFu + ((u >> 16) & 1u)) >> 16);
}
__device__ __forceinline__ float bf2f(unsigned short h) {
  return __uint_as_float(((uint32_t)h) << 16);
}

// prep: per-node A tables (64B/node: A1h0 A1h1 A2h0 A2h1), |v|^2 folded into
// A2h1 slots 3..5 (3-split) with B=1.0; slots 6..7 = 1.0 for the sp pair.
__global__ void dg_prep(const float* __restrict__ vd,
                        unsigned short* __restrict__ aF) {
  const int j = blockIdx.x * 256 + threadIdx.x;
  const float v0 = vd[j * 3 + 0], v1 = vd[j * 3 + 1], v2 = vd[j * 3 + 2];
  unsigned short H[3], M[3], L[3];
  const float vc[3] = {v0, v1, v2};
#pragma unroll
  for (int c = 0; c < 3; ++c) {
    H[c] = f2bf(vc[c]);
    const float r1 = vc[c] - bf2f(H[c]);
    M[c] = f2bf(r1);
    const float r2 = r1 - bf2f(M[c]);
    L[c] = f2bf(r2);
  }
  const float sv = v0 * v0 + v1 * v1 + v2 * v2;
  const unsigned short svH = f2bf(sv);
  const float rs1 = sv - bf2f(svH);
  const unsigned short svM = f2bf(rs1);
  const unsigned short svL = f2bf(rs1 - bf2f(svM));

  unsigned short* o = aF + j * 32;
  o[0]=H[0]; o[1]=H[1]; o[2]=H[2]; o[3]=M[0]; o[4]=M[1]; o[5]=M[2];
  o[6]=L[0]; o[7]=L[1]; o[8]=L[2]; o[9]=H[0]; o[10]=H[1]; o[11]=H[2];
  o[12]=M[0]; o[13]=M[1]; o[14]=M[2]; o[15]=L[0];
  o[16]=L[1]; o[17]=L[2]; o[18]=H[0]; o[19]=H[1]; o[20]=H[2];
  o[21]=M[0]; o[22]=M[1]; o[23]=M[2];
  o[24]=L[0]; o[25]=L[1]; o[26]=L[2];
  o[27]=(unsigned short)svH; o[28]=(unsigned short)svM; o[29]=(unsigned short)svL;
  o[30]=0x3F80; o[31]=0x3F80;
}

__global__ __launch_bounds__(BT, 2) void dg_mfma(
    const float* __restrict__ inp, const float* __restrict__ vd,
    const float* __restrict__ Rm, const float* __restrict__ gv,
    const float* __restrict__ tv, const short8* __restrict__ aF,
    float* __restrict__ out)
{
  __shared__ uint32_t st[CAP * BT];        // 32 KB per-lane stacks
  __shared__ uint32_t thrK[64];            // per-point global running k19
  const int tid  = threadIdx.x;
  const int lane = tid & 63;
  const int col  = lane & 31;              // point within wave's 32
  const int h    = lane >> 5;              // k-half / row-group bit
  const int wv   = tid >> 6;
  const int half = wv & 1;                 // node half (2048 nodes)
  const int pg   = wv >> 1;                // point group (32 points)
  const int P    = pg * 32 + col;          // block-local point id (0..63)
  const int gi   = blockIdx.x * 64 + P;

  if (tid < 64) thrK[tid] = 0xFFFFFFFFu;
  __syncthreads();

  const float p0 = inp[gi * 35 + 0];
  const float p1 = inp[gi * 35 + 1];
  const float p2 = inp[gi * 35 + 2];
  const float sp = p0 * p0 + p1 * p1 + p2 * p2;

  // 3-way split of (-2p); 2-way split of sp (constant per-point offset ->
  // order-invariant within the point's candidate set).
  unsigned short qH[3], qM[3], qL[3], spH, spM;
  {
    const float qc[3] = {-2.0f * p0, -2.0f * p1, -2.0f * p2};
#pragma unroll
    for (int c = 0; c < 3; ++c) {
      qH[c] = f2bf(qc[c]);
      const float r1 = qc[c] - bf2f(qH[c]);
      qM[c] = f2bf(r1);
      const float r2 = r1 - bf2f(qM[c]);
      qL[c] = f2bf(r2);
    }
    spH = f2bf(sp);
    spM = f2bf(sp - bf2f(spH));
  }
  short8 b1, b2;
  if (h == 0) {
    b1[0]=qH[0]; b1[1]=qH[1]; b1[2]=qH[2]; b1[3]=qH[0];
    b1[4]=qH[1]; b1[5]=qH[2]; b1[6]=qH[0]; b1[7]=qH[1];
    b2[0]=qM[1]; b2[1]=qM[2]; b2[2]=qL[0]; b2[3]=qL[1];
    b2[4]=qL[2]; b2[5]=qL[0]; b2[6]=qL[1]; b2[7]=qL[2];
  } else {
    b1[0]=qH[2]; b1[1]=qM[0]; b1[2]=qM[1]; b1[3]=qM[2];
    b1[4]=qM[0]; b1[5]=qM[1]; b1[6]=qM[2]; b1[7]=qM[0];
    b2[0]=qL[0]; b2[1]=qL[1]; b2[2]=qL[2];
    b2[3]=(short)0x3F80; b2[4]=(short)0x3F80; b2[5]=(short)0x3F80;
    b2[6]=(short)spH; b2[7]=(short)spM;
  }

  uint32_t m[KSEL];                        // invariant: ascending sorted
#pragma unroll
  for (int k = 0; k < KSEL; ++k) m[k] = 0xFFFFFFFFu;
  uint32_t cnt = 0;
  float thr = __uint_as_float(0x7F7FFFFFu);

  // batch drain: stack -> c[32] (UINT_MAX pad) -> FULL sort -> half-cleaner
  // merge with sorted m (pairwise min) -> sort32 -> new sorted m. Then
  // publish pair-k19 to the point-global thrK (monotone atomicMin).
  auto drain = [&]() {
    uint32_t c[32];
#pragma unroll
    for (int u = 0; u < 32; ++u) {
      const uint32_t x = st[u * BT + tid];
      c[u] = ((uint32_t)u < cnt) ? x : 0xFFFFFFFFu;
    }
    bsort32(c);                            // arbitrary -> ascending
#pragma unroll
    for (int k = 0; k < 16; ++k) {
      const uint32_t mk  = (k < KSEL)        ? m[k]      : 0xFFFFFFFFu;
      const uint32_t mk2 = ((31 - k) < KSEL) ? m[31 - k] : 0xFFFFFFFFu;
      const uint32_t t1 = umin32(mk,  c[31 - k]);
      const uint32_t t2 = umin32(mk2, c[k]);
      c[k]      = t1;
      c[31 - k] = t2;
    }
    sort32(c);                             // bitonic -> ascending
#pragma unroll
    for (int k = 0; k < KSEL; ++k) m[k] = c[k];
    cnt = 0;
    uint32_t k19 = m[KSEL - 1];
    k19 = umin32(k19, (uint32_t)__shfl_xor((int)k19, 32));  // pair share
    // cross-half share (monotone, race-safe: stale = larger = over-collect)
    const uint32_t old = atomicMin(&thrK[P], k19);
    thr = thr_from(umin32(old, k19));
  };

  f32x16 zacc;
#pragma unroll
  for (int i = 0; i < 16; ++i) zacc[i] = 0.0f;

  uint32_t nb = 0;
  auto process = [&](const f32x16& acc) {
#pragma unroll
    for (int i = 0; i < 16; ++i) {
      const float d = acc[i];
      const uint32_t key =
          ((__float_as_uint(fmaxf(d, 0.0f)) & 0xFFFFF800u) << 1)
          + (nb + (uint32_t)((i & 3) + 8 * (i >> 2)));
      st[cnt * BT + tid] = key;
      cnt += (uint32_t)(d < thr);
    }
    if (__any((int)(cnt > 16))) drain();   // 16+16 = 32 fits CAP exactly
    nb += 32;
  };

  const int T0 = half * 64;                 // 64 tiles of 32 nodes per half
  const short8* ap = aF + ((T0 * 32 + col) * 4 + h);
  nb = (uint32_t)(T0 * 32 + 4 * h);

  // ---- software-pipelined scan (2 tiles in flight) ----
  short8 a1A = ap[0], a2A = ap[2]; ap += 128;       // tile 0
  f32x16 accA = __builtin_amdgcn_mfma_f32_32x32x16_bf16(a1A, b1, zacc, 0, 0, 0);
  accA = __builtin_amdgcn_mfma_f32_32x32x16_bf16(a2A, b2, accA, 0, 0, 0);
  short8 a1B = ap[0], a2B = ap[2]; ap += 128;       // tile 1 loads
  f32x16 accB;

#pragma unroll 1
  for (int k = 0; k < 31; ++k) {
    accB = __builtin_amdgcn_mfma_f32_32x32x16_bf16(a1B, b1, zacc, 0, 0, 0);
    accB = __builtin_amdgcn_mfma_f32_32x32x16_bf16(a2B, b2, accB, 0, 0, 0);
    a1A = ap[0]; a2A = ap[2]; ap += 128;            // loads tile 2k+2
    process(accA);                                   // tile 2k
    accA = __builtin_amdgcn_mfma_f32_32x32x16_bf16(a1A, b1, zacc, 0, 0, 0);
    accA = __builtin_amdgcn_mfma_f32_32x32x16_bf16(a2A, b2, accA, 0, 0, 0);
    a1B = ap[0]; a2B = ap[2]; ap += 128;            // loads tile 2k+3
    process(accB);                                   // tile 2k+1
  }
  accB = __builtin_amdgcn_mfma_f32_32x32x16_bf16(a1B, b1, zacc, 0, 0, 0);
  accB = __builtin_amdgcn_mfma_f32_32x32x16_bf16(a2B, b2, accB, 0, 0, 0);
  process(accA);                                     // tile 62
  process(accB);                                     // tile 63
  drain();

  // ---- pair merge (lane l <-> l^32): sorted top-20 of this half ----
  uint32_t arr[32];
#pragma unroll
  for (int k = 0; k < KSEL; ++k) arr[k] = m[k];
#pragma unroll
  for (int k = KSEL; k < 32; ++k) arr[k] = 0xFFFFFFFFu;
#pragma unroll
  for (int k = 0; k < 16; ++k) {
    const uint32_t sa = (uint32_t)__shfl_xor((int)arr[k],      32);
    const uint32_t sb = (uint32_t)__shfl_xor((int)arr[31 - k], 32);
    arr[k]      = umin32(arr[k],      sb);
    arr[31 - k] = umin32(arr[31 - k], sa);
  }
  sort32(arr);                             // inputs sorted -> bitonic: valid

  // ---- cross-wave merge over node halves ----
  __syncthreads();                          // stacks dead; reuse st
  if (half == 1 && h == 0) {
    uint32_t* mb = st + P * KSEL;
#pragma unroll
    for (int k = 0; k < KSEL; ++k) mb[k] = arr[k];
  }
  __syncthreads();
  if (half == 1) return;

  uint32_t sset[KSEL];
  {
    const uint32_t* mb = st + P * KSEL;
#pragma unroll
    for (int k = 0; k < KSEL; ++k)
      sset[k] = umin32(arr[k], mb[KSEL - 1 - k]);   // top-20 SET (unsorted)
  }

  // ---- distributed exact recompute: lane h handles k = 2s+h, s=0..9 ----
  int   id10[10];
  float d10[10];
  float dmn = 1e30f, dmx = -1e30f;
#pragma unroll
  for (int s = 0; s < 10; ++s) {
    const int idk = (int)(sset[2 * s + h] & 0xFFFu);
    id10[s] = idk;
    const float v0 = vd[idk * 3 + 0];
    const float v1 = vd[idk * 3 + 1];
    const float v2 = vd[idk * 3 + 2];
    const float sv2 = v0 * v0 + v1 * v1 + v2 * v2;
    const float dt  = p0 * v0 + p1 * v1 + p2 * v2;
    const float ddx = (sp + sv2) - 2.0f * dt;       // reference formula
    d10[s] = ddx;
    dmn = fminf(dmn, ddx);
    dmx = fmaxf(dmx, ddx);
  }
  dmx = fmaxf(dmx, __shfl_xor(dmx, 32));
  dmn = fminf(dmn, __shfl_xor(dmn, 32));

  const float invmax = 1.0f / dmx;
  float wsum = 0.0f, pb0 = 0.0f, pb1 = 0.0f, pb2 = 0.0f;
  float rb[9];
#pragma unroll
  for (int a2i = 0; a2i < 9; ++a2i) rb[a2i] = 0.0f;

#pragma unroll
  for (int s = 0; s < 10; ++s) {
    const int idk = id10[s];
    const float u = 1.0f - d10[s] * invmax;
    const float w = u * u;
    wsum += w;
    const float* Rp = Rm + idk * 9;
    const float r00 = Rp[0], r01 = Rp[1], r02 = Rp[2];
    const float r10 = Rp[3], r11 = Rp[4], r12 = Rp[5];
    const float r20 = Rp[6], r21 = Rp[7], r22 = Rp[8];
    const float g0 = gv[idk * 3 + 0];
    const float g1 = gv[idk * 3 + 1];
    const float g2 = gv[idk * 3 + 2];
    const float t0 = tv[idk * 3 + 0];
    const float t1 = tv[idk * 3 + 1];
    const float t2 = tv[idk * 3 + 2];
    const float x0 = p0 - g0 - t0;
    const float x1 = p1 - g1 - t1;
    const float x2 = p2 - g2 - t2;
    pb0 += w * (r00 * x0 + r10 * x1 + r20 * x2 + g0);
    pb1 += w * (r01 * x0 + r11 * x1 + r21 * x2 + g1);
    pb2 += w * (r02 * x0 + r12 * x1 + r22 * x2 + g2);
    rb[0] += w * r00; rb[1] += w * r10; rb[2] += w * r20;
    rb[3] += w * r01; rb[4] += w * r11; rb[5] += w * r21;
    rb[6] += w * r02; rb[7] += w * r12; rb[8] += w * r22;
  }

  wsum += __shfl_xor(wsum, 32);
  pb0  += __shfl_xor(pb0, 32);
  pb1  += __shfl_xor(pb1, 32);
  pb2  += __shfl_xor(pb2, 32);
#pragma unroll
  for (int a2i = 0; a2i < 9; ++a2i) rb[a2i] += __shfl_xor(rb[a2i], 32);

  if (h == 0) {
    const float inw = 1.0f / wsum;
    float o0 = pb0 * inw;
    if (dmn > 0.00021f) o0 = 1000000000.0f;
    float* po = out + (size_t)gi * 3;
    po[0] = o0; po[1] = pb1 * inw; po[2] = pb2 * inw;
    float* ro = out + (size_t)NPTS * 3 + (size_t)gi * 9;
#pragma unroll
    for (int a2i = 0; a2i < 9; ++a2i) ro[a2i] = rb[a2i] * inw;
  }
}

// ---- fallback: R2-style scalar kernel (proven), if ws too small ----
__global__ __launch_bounds__(256, 4) void dg_fb(
    const float* __restrict__ inp, const float* __restrict__ vd,
    const float* __restrict__ Rm, const float* __restrict__ gv,
    const float* __restrict__ tv, float* __restrict__ out)
{
  __shared__ uint32_t st[33 * 256];
  const int tid = threadIdx.x;
  const int q   = (tid >> 4) & 3;
  const int pl  = tid & 15;
  const int wv  = tid >> 6;
  const int gi  = blockIdx.x * 64 + wv * 16 + pl;
  const float p0 = inp[gi * 35 + 0];
  const float p1 = inp[gi * 35 + 1];
  const float p2 = inp[gi * 35 + 2];
  const float sp = p0 * p0 + p1 * p1 + p2 * p2;
  uint32_t m[KSEL];
#pragma unroll
  for (int k = 0; k < KSEL; ++k) m[k] = 0xFFFFFFFFu;
  int cnt = 0;
  float thr = __uint_as_float(0x7F7FFFFFu);
  const int jbase = q * (NNODES / 4);
  int lo = 0;
#pragma unroll
  for (int c = 0; c < 6; ++c) {
    const int hi = 32 << c;
    for (int i = lo; i < hi; ++i) {
      const int j = jbase + i;
      const float v0 = vd[j * 3 + 0], v1 = vd[j * 3 + 1], v2 = vd[j * 3 + 2];
      const float sv = v0 * v0 + v1 * v1 + v2 * v2;
      const float dt = p0 * v0 + p1 * v1 + p2 * v2;
      float d2 = fmaxf((sp + sv) - 2.0f * dt, 0.0f);
      if (d2 < thr) {
        st[cnt * 256 + tid] = ((__float_as_uint(d2) & 0xFFFFF800u) << 1) | (uint32_t)j;
        if (++cnt == 33) {
          for (int u = 0; u < cnt; ++u) {
            const uint32_t x = st[u * 256 + tid];
            if (x < m[KSEL - 1]) insert20(m, x);
          }
          cnt = 0; thr = thr_from(m[KSEL - 1]);
        }
      }
    }
    for (int u = 0; u < cnt; ++u) {
      const uint32_t x = st[u * 256 + tid];
      if (x < m[KSEL - 1]) insert20(m, x);
    }
    cnt = 0; thr = thr_from(m[KSEL - 1]); lo = hi;
  }
  uint32_t arr[32];
#pragma unroll
  for (int k = 0; k < KSEL; ++k) arr[k] = m[k];
#pragma unroll
  for (int k = KSEL; k < 32; ++k) arr[k] = 0xFFFFFFFFu;
#pragma unroll
  for (int mask = 32; mask >= 16; mask >>= 1) {
#pragma unroll
    for (int k = 0; k < 16; ++k) {
      const uint32_t sa = (uint32_t)__shfl_xor((int)arr[k],      mask);
      const uint32_t sb = (uint32_t)__shfl_xor((int)arr[31 - k], mask);
      arr[k]      = umin32(arr[k],      sb);
      arr[31 - k] = umin32(arr[31 - k], sa);
    }
#pragma unroll
    for (int dd = 16; dd >= 1; dd >>= 1)
#pragma unroll
      for (int k = 0; k < 32; ++k)
        if ((k & dd) == 0) cmpswap(arr[k], arr[k | dd]);
  }
  int id5[5]; float d5[5];
  float dmn = 1e30f, dmx = -1e30f;
#pragma unroll
  for (int s = 0; s < 5; ++s) {
    const int idk = (int)(arr[4 * s + q] & 0xFFFu);
    id5[s] = idk;
    const float v0 = vd[idk * 3 + 0], v1 = vd[idk * 3 + 1], v2 = vd[idk * 3 + 2];
    const float sv = v0 * v0 + v1 * v1 + v2 * v2;
    const float dt = p0 * v0 + p1 * v1 + p2 * v2;
    const float ddx = (sp + sv) - 2.0f * dt;
    d5[s] = ddx; dmn = fminf(dmn, ddx); dmx = fmaxf(dmx, ddx);
  }
#pragma unroll
  for (int r = 16; r <= 32; r <<= 1) {
    dmx = fmaxf(dmx, __shfl_xor(dmx, r));
    dmn = fminf(dmn, __shfl_xor(dmn, r));
  }
  const float invmax = 1.0f / dmx;
  float wsum = 0.0f, pb0 = 0.0f, pb1 = 0.0f, pb2 = 0.0f;
  float rb[9];
#pragma unroll
  for (int a2i = 0; a2i < 9; ++a2i) rb[a2i] = 0.0f;
#pragma unroll
  for (int s = 0; s < 5; ++s) {
    const int idk = id5[s];
    const float u = 1.0f - d5[s] * invmax;
    const float w = u * u;
    wsum += w;
    const float* Rp = Rm + idk * 9;
    const float r00 = Rp[0], r01 = Rp[1], r02 = Rp[2];
    const float r10 = Rp[3], r11 = Rp[4], r12 = Rp[5];
    const float r20 = Rp[6], r21 = Rp[7], r22 = Rp[8];
    const float g0 = gv[idk * 3 + 0], g1 = gv[idk * 3 + 1], g2 = gv[idk * 3 + 2];
    const float t0 = tv[idk * 3 + 0], t1 = tv[idk * 3 + 1], t2 = tv[idk * 3 + 2];
    const float x0 = p0 - g0 - t0, x1 = p1 - g1 - t1, x2 = p2 - g2 - t2;
    pb0 += w * (r00 * x0 + r10 * x1 + r20 * x2 + g0);
    pb1 += w * (r01 * x0 + r11 * x1 + r21 * x2 + g1);
    pb2 += w * (r02 * x0 + r12 * x1 + r22 * x2 + g2);
    rb[0] += w * r00; rb[1] += w * r10; rb[2] += w * r20;
    rb[3] += w * r01; rb[4] += w * r11; rb[5] += w * r21;
    rb[6] += w * r02; rb[7] += w * r12; rb[8] += w * r22;
  }
#pragma unroll
  for (int r = 16; r <= 32; r <<= 1) {
    wsum += __shfl_xor(wsum, r);
    pb0 += __shfl_xor(pb0, r);
    pb1 += __shfl_xor(pb1, r);
    pb2 += __shfl_xor(pb2, r);
#pragma unroll
    for (int a2i = 0; a2i < 9; ++a2i) rb[a2i] += __shfl_xor(rb[a2i], r);
  }
  if (q == 0) {
    const float inw = 1.0f / wsum;
    float o0 = pb0 * inw;
    if (dmn > 0.00021f) o0 = 1000000000.0f;
    float* po = out + (size_t)gi * 3;
    po[0] = o0; po[1] = pb1 * inw; po[2] = pb2 * inw;
    float* ro = out + (size_t)NPTS * 3 + (size_t)gi * 9;
#pragma unroll
    for (int a2i = 0; a2i < 9; ++a2i) ro[a2i] = rb[a2i] * inw;
  }
}

extern "C" void kernel_launch(void* const* d_in, const int* in_sizes, int n_in,
                              void* d_out, int out_size, void* d_ws, size_t ws_size,
                              hipStream_t stream) {
  const float* inp = (const float*)d_in[0];
  const float* vd  = (const float*)d_in[1];
  const float* Rm  = (const float*)d_in[2];
  const float* gv  = (const float*)d_in[3];
  const float* tv  = (const float*)d_in[4];
  float* out = (float*)d_out;

  if (ws_size >= (size_t)WS_NEEDED) {
    unsigned short* aF = (unsigned short*)d_ws;
    dg_prep<<<NNODES / 256, 256, 0, stream>>>(vd, aF);
    dg_mfma<<<NPTS / 64, BT, 0, stream>>>(inp, vd, Rm, gv, tv,
                                          (const short8*)aF, out);
  } else {
    dg_fb<<<NPTS / 64, 256, 0, stream>>>(inp, vd, Rm, gv, tv, out);
  }
}

// Round 15
// 135.437 us; speedup vs baseline: 1.0712x; 1.0712x over previous
//
#include <hip/hip_runtime.h>
#include <stdint.h>

// DeformationGraph R15 = R13 exact revert (best-correct: 136us).
//  R14 lesson: __launch_bounds__(256,2) let VGPR grow 64->88 but the compiler
//  spent the headroom on longer live ranges; measured occupancy fell 29->18.7%
//  and dur regressed to 145us. (256,4)/VGPR=64 is the empirical optimum.
//  Structure (R13): 32x32 MFMA scan (2 chained mfma_f32_32x32x16_bf16,
//  3-way bf16-split fp32-exact dot, sp+sv folded into spare K-slots, x2
//  software pipeline, branchless push), batch-sorted drains (bsort32 full
//  Batcher sort -> half-cleaner merge with sorted m[20] -> sort32),
//  point-global threshold via LDS atomicMin (monotone, race-safe),
//  256-thr blocks (2 point-groups x 2 node-halves), pair/cross-half merges,
//  exact fp32 reference-formula recompute of the selected 20 (far-flag
//  razor edge), distributed blend.

#define NPTS   65536
#define NNODES 4096
#define KSEL   20
#define CAP    32
#define BT     256
#define AFRAG_BYTES  (NNODES * 64)
#define WS_NEEDED    AFRAG_BYTES

typedef __attribute__((ext_vector_type(8)))  short short8;
typedef __attribute__((ext_vector_type(16))) float f32x16;

__device__ __forceinline__ uint32_t umin32(uint32_t a, uint32_t b) { return a < b ? a : b; }
__device__ __forceinline__ uint32_t umax32(uint32_t a, uint32_t b) { return a > b ? a : b; }
__device__ __forceinline__ void cmpswap(uint32_t& a, uint32_t& b) {
  const uint32_t lo = umin32(a, b), hi = umax32(a, b); a = lo; b = hi;
}
// bitonic MERGE network: sorts a 32-length BITONIC sequence ascending.
__device__ __forceinline__ void sort32(uint32_t arr[32]) {
#pragma unroll
  for (int dd = 16; dd >= 1; dd >>= 1)
#pragma unroll
    for (int k = 0; k < 32; ++k)
      if ((k & dd) == 0) cmpswap(arr[k], arr[k | dd]);
}
// full Batcher bitonic SORT network: sorts an ARBITRARY 32-seq ascending.
__device__ __forceinline__ void bsort32(uint32_t a[32]) {
#pragma unroll
  for (int k = 2; k <= 32; k <<= 1) {
#pragma unroll
    for (int j = k >> 1; j > 0; j >>= 1) {
#pragma unroll
      for (int i = 0; i < 32; ++i) {
        const int l = i ^ j;
        if (l > i) {
          if ((i & k) == 0) cmpswap(a[i], a[l]);   // ascending block
          else              cmpswap(a[l], a[i]);   // descending block
        }
      }
    }
  }
}
__device__ __forceinline__ void insert20(uint32_t m[KSEL], uint32_t x) {
#pragma unroll
  for (int k = KSEL - 1; k >= 1; --k)
    m[k] = umin32(m[k], umax32(m[k - 1], x));
  m[0] = umin32(m[0], x);
}
__device__ __forceinline__ float thr_from(uint32_t m19) {
  return __uint_as_float(umin32((m19 >> 12) << 11, 0x7F7FFFFFu));
}
__device__ __forceinline__ unsigned short f2bf(float x) {   // RNE fp32->bf16
  uint32_t u = __float_as_uint(x);
  return (unsigned short)((u + 0x7FFFu + ((u >> 16) & 1u)) >> 16);
}
__device__ __forceinline__ float bf2f(unsigned short h) {
  return __uint_as_float(((uint32_t)h) << 16);
}

// prep: per-node A tables (64B/node: A1h0 A1h1 A2h0 A2h1), |v|^2 folded into
// A2h1 slots 3..5 (3-split) with B=1.0; slots 6..7 = 1.0 for the sp pair.
__global__ void dg_prep(const float* __restrict__ vd,
                        unsigned short* __restrict__ aF) {
  const int j = blockIdx.x * 256 + threadIdx.x;
  const float v0 = vd[j * 3 + 0], v1 = vd[j * 3 + 1], v2 = vd[j * 3 + 2];
  unsigned short H[3], M[3], L[3];
  const float vc[3] = {v0, v1, v2};
#pragma unroll
  for (int c = 0; c < 3; ++c) {
    H[c] = f2bf(vc[c]);
    const float r1 = vc[c] - bf2f(H[c]);
    M[c] = f2bf(r1);
    const float r2 = r1 - bf2f(M[c]);
    L[c] = f2bf(r2);
  }
  const float sv = v0 * v0 + v1 * v1 + v2 * v2;
  const unsigned short svH = f2bf(sv);
  const float rs1 = sv - bf2f(svH);
  const unsigned short svM = f2bf(rs1);
  const unsigned short svL = f2bf(rs1 - bf2f(svM));

  unsigned short* o = aF + j * 32;
  o[0]=H[0]; o[1]=H[1]; o[2]=H[2]; o[3]=M[0]; o[4]=M[1]; o[5]=M[2];
  o[6]=L[0]; o[7]=L[1]; o[8]=L[2]; o[9]=H[0]; o[10]=H[1]; o[11]=H[2];
  o[12]=M[0]; o[13]=M[1]; o[14]=M[2]; o[15]=L[0];
  o[16]=L[1]; o[17]=L[2]; o[18]=H[0]; o[19]=H[1]; o[20]=H[2];
  o[21]=M[0]; o[22]=M[1]; o[23]=M[2];
  o[24]=L[0]; o[25]=L[1]; o[26]=L[2];
  o[27]=(unsigned short)svH; o[28]=(unsigned short)svM; o[29]=(unsigned short)svL;
  o[30]=0x3F80; o[31]=0x3F80;
}

__global__ __launch_bounds__(BT, 4) void dg_mfma(
    const float* __restrict__ inp, const float* __restrict__ vd,
    const float* __restrict__ Rm, const float* __restrict__ gv,
    const float* __restrict__ tv, const short8* __restrict__ aF,
    float* __restrict__ out)
{
  __shared__ uint32_t st[CAP * BT];        // 32 KB per-lane stacks
  __shared__ uint32_t thrK[64];            // per-point global running k19
  const int tid  = threadIdx.x;
  const int lane = tid & 63;
  const int col  = lane & 31;              // point within wave's 32
  const int h    = lane >> 5;              // k-half / row-group bit
  const int wv   = tid >> 6;
  const int half = wv & 1;                 // node half (2048 nodes)
  const int pg   = wv >> 1;                // point group (32 points)
  const int P    = pg * 32 + col;          // block-local point id (0..63)
  const int gi   = blockIdx.x * 64 + P;

  if (tid < 64) thrK[tid] = 0xFFFFFFFFu;
  __syncthreads();

  const float p0 = inp[gi * 35 + 0];
  const float p1 = inp[gi * 35 + 1];
  const float p2 = inp[gi * 35 + 2];
  const float sp = p0 * p0 + p1 * p1 + p2 * p2;

  // 3-way split of (-2p); 2-way split of sp (constant per-point offset ->
  // order-invariant within the point's candidate set).
  unsigned short qH[3], qM[3], qL[3], spH, spM;
  {
    const float qc[3] = {-2.0f * p0, -2.0f * p1, -2.0f * p2};
#pragma unroll
    for (int c = 0; c < 3; ++c) {
      qH[c] = f2bf(qc[c]);
      const float r1 = qc[c] - bf2f(qH[c]);
      qM[c] = f2bf(r1);
      const float r2 = r1 - bf2f(qM[c]);
      qL[c] = f2bf(r2);
    }
    spH = f2bf(sp);
    spM = f2bf(sp - bf2f(spH));
  }
  short8 b1, b2;
  if (h == 0) {
    b1[0]=qH[0]; b1[1]=qH[1]; b1[2]=qH[2]; b1[3]=qH[0];
    b1[4]=qH[1]; b1[5]=qH[2]; b1[6]=qH[0]; b1[7]=qH[1];
    b2[0]=qM[1]; b2[1]=qM[2]; b2[2]=qL[0]; b2[3]=qL[1];
    b2[4]=qL[2]; b2[5]=qL[0]; b2[6]=qL[1]; b2[7]=qL[2];
  } else {
    b1[0]=qH[2]; b1[1]=qM[0]; b1[2]=qM[1]; b1[3]=qM[2];
    b1[4]=qM[0]; b1[5]=qM[1]; b1[6]=qM[2]; b1[7]=qM[0];
    b2[0]=qL[0]; b2[1]=qL[1]; b2[2]=qL[2];
    b2[3]=(short)0x3F80; b2[4]=(short)0x3F80; b2[5]=(short)0x3F80;
    b2[6]=(short)spH; b2[7]=(short)spM;
  }

  uint32_t m[KSEL];                        // invariant: ascending sorted
#pragma unroll
  for (int k = 0; k < KSEL; ++k) m[k] = 0xFFFFFFFFu;
  uint32_t cnt = 0;
  float thr = __uint_as_float(0x7F7FFFFFu);

  // batch drain: stack -> c[32] (UINT_MAX pad) -> FULL sort -> half-cleaner
  // merge with sorted m (pairwise min) -> sort32 -> new sorted m. Then
  // publish pair-k19 to the point-global thrK (monotone atomicMin).
  auto drain = [&]() {
    uint32_t c[32];
#pragma unroll
    for (int u = 0; u < 32; ++u) {
      const uint32_t x = st[u * BT + tid];
      c[u] = ((uint32_t)u < cnt) ? x : 0xFFFFFFFFu;
    }
    bsort32(c);                            // arbitrary -> ascending
#pragma unroll
    for (int k = 0; k < 16; ++k) {
      const uint32_t mk  = (k < KSEL)        ? m[k]      : 0xFFFFFFFFu;
      const uint32_t mk2 = ((31 - k) < KSEL) ? m[31 - k] : 0xFFFFFFFFu;
      const uint32_t t1 = umin32(mk,  c[31 - k]);
      const uint32_t t2 = umin32(mk2, c[k]);
      c[k]      = t1;
      c[31 - k] = t2;
    }
    sort32(c);                             // bitonic -> ascending
#pragma unroll
    for (int k = 0; k < KSEL; ++k) m[k] = c[k];
    cnt = 0;
    uint32_t k19 = m[KSEL - 1];
    k19 = umin32(k19, (uint32_t)__shfl_xor((int)k19, 32));  // pair share
    // cross-half share (monotone, race-safe: stale = larger = over-collect)
    const uint32_t old = atomicMin(&thrK[P], k19);
    thr = thr_from(umin32(old, k19));
  };

  f32x16 zacc;
#pragma unroll
  for (int i = 0; i < 16; ++i) zacc[i] = 0.0f;

  uint32_t nb = 0;
  auto process = [&](const f32x16& acc) {
#pragma unroll
    for (int i = 0; i < 16; ++i) {
      const float d = acc[i];
      const uint32_t key =
          ((__float_as_uint(fmaxf(d, 0.0f)) & 0xFFFFF800u) << 1)
          + (nb + (uint32_t)((i & 3) + 8 * (i >> 2)));
      st[cnt * BT + tid] = key;
      cnt += (uint32_t)(d < thr);
    }
    if (__any((int)(cnt > 16))) drain();   // 16+16 = 32 fits CAP exactly
    nb += 32;
  };

  const int T0 = half * 64;                 // 64 tiles of 32 nodes per half
  const short8* ap = aF + ((T0 * 32 + col) * 4 + h);
  nb = (uint32_t)(T0 * 32 + 4 * h);

  // ---- software-pipelined scan (2 tiles in flight) ----
  short8 a1A = ap[0], a2A = ap[2]; ap += 128;       // tile 0
  f32x16 accA = __builtin_amdgcn_mfma_f32_32x32x16_bf16(a1A, b1, zacc, 0, 0, 0);
  accA = __builtin_amdgcn_mfma_f32_32x32x16_bf16(a2A, b2, accA, 0, 0, 0);
  short8 a1B = ap[0], a2B = ap[2]; ap += 128;       // tile 1 loads
  f32x16 accB;

#pragma unroll 1
  for (int k = 0; k < 31; ++k) {
    accB = __builtin_amdgcn_mfma_f32_32x32x16_bf16(a1B, b1, zacc, 0, 0, 0);
    accB = __builtin_amdgcn_mfma_f32_32x32x16_bf16(a2B, b2, accB, 0, 0, 0);
    a1A = ap[0]; a2A = ap[2]; ap += 128;            // loads tile 2k+2
    process(accA);                                   // tile 2k
    accA = __builtin_amdgcn_mfma_f32_32x32x16_bf16(a1A, b1, zacc, 0, 0, 0);
    accA = __builtin_amdgcn_mfma_f32_32x32x16_bf16(a2A, b2, accA, 0, 0, 0);
    a1B = ap[0]; a2B = ap[2]; ap += 128;            // loads tile 2k+3
    process(accB);                                   // tile 2k+1
  }
  accB = __builtin_amdgcn_mfma_f32_32x32x16_bf16(a1B, b1, zacc, 0, 0, 0);
  accB = __builtin_amdgcn_mfma_f32_32x32x16_bf16(a2B, b2, accB, 0, 0, 0);
  process(accA);                                     // tile 62
  process(accB);                                     // tile 63
  drain();

  // ---- pair merge (lane l <-> l^32): sorted top-20 of this half ----
  uint32_t arr[32];
#pragma unroll
  for (int k = 0; k < KSEL; ++k) arr[k] = m[k];
#pragma unroll
  for (int k = KSEL; k < 32; ++k) arr[k] = 0xFFFFFFFFu;
#pragma unroll
  for (int k = 0; k < 16; ++k) {
    const uint32_t sa = (uint32_t)__shfl_xor((int)arr[k],      32);
    const uint32_t sb = (uint32_t)__shfl_xor((int)arr[31 - k], 32);
    arr[k]      = umin32(arr[k],      sb);
    arr[31 - k] = umin32(arr[31 - k], sa);
  }
  sort32(arr);                             // inputs sorted -> bitonic: valid

  // ---- cross-wave merge over node halves ----
  __syncthreads();                          // stacks dead; reuse st
  if (half == 1 && h == 0) {
    uint32_t* mb = st + P * KSEL;
#pragma unroll
    for (int k = 0; k < KSEL; ++k) mb[k] = arr[k];
  }
  __syncthreads();
  if (half == 1) return;

  uint32_t sset[KSEL];
  {
    const uint32_t* mb = st + P * KSEL;
#pragma unroll
    for (int k = 0; k < KSEL; ++k)
      sset[k] = umin32(arr[k], mb[KSEL - 1 - k]);   // top-20 SET (unsorted)
  }

  // ---- distributed exact recompute: lane h handles k = 2s+h, s=0..9 ----
  int   id10[10];
  float d10[10];
  float dmn = 1e30f, dmx = -1e30f;
#pragma unroll
  for (int s = 0; s < 10; ++s) {
    const int idk = (int)(sset[2 * s + h] & 0xFFFu);
    id10[s] = idk;
    const float v0 = vd[idk * 3 + 0];
    const float v1 = vd[idk * 3 + 1];
    const float v2 = vd[idk * 3 + 2];
    const float sv2 = v0 * v0 + v1 * v1 + v2 * v2;
    const float dt  = p0 * v0 + p1 * v1 + p2 * v2;
    const float ddx = (sp + sv2) - 2.0f * dt;       // reference formula
    d10[s] = ddx;
    dmn = fminf(dmn, ddx);
    dmx = fmaxf(dmx, ddx);
  }
  dmx = fmaxf(dmx, __shfl_xor(dmx, 32));
  dmn = fminf(dmn, __shfl_xor(dmn, 32));

  const float invmax = 1.0f / dmx;
  float wsum = 0.0f, pb0 = 0.0f, pb1 = 0.0f, pb2 = 0.0f;
  float rb[9];
#pragma unroll
  for (int a2i = 0; a2i < 9; ++a2i) rb[a2i] = 0.0f;

#pragma unroll
  for (int s = 0; s < 10; ++s) {
    const int idk = id10[s];
    const float u = 1.0f - d10[s] * invmax;
    const float w = u * u;
    wsum += w;
    const float* Rp = Rm + idk * 9;
    const float r00 = Rp[0], r01 = Rp[1], r02 = Rp[2];
    const float r10 = Rp[3], r11 = Rp[4], r12 = Rp[5];
    const float r20 = Rp[6], r21 = Rp[7], r22 = Rp[8];
    const float g0 = gv[idk * 3 + 0];
    const float g1 = gv[idk * 3 + 1];
    const float g2 = gv[idk * 3 + 2];
    const float t0 = tv[idk * 3 + 0];
    const float t1 = tv[idk * 3 + 1];
    const float t2 = tv[idk * 3 + 2];
    const float x0 = p0 - g0 - t0;
    const float x1 = p1 - g1 - t1;
    const float x2 = p2 - g2 - t2;
    pb0 += w * (r00 * x0 + r10 * x1 + r20 * x2 + g0);
    pb1 += w * (r01 * x0 + r11 * x1 + r21 * x2 + g1);
    pb2 += w * (r02 * x0 + r12 * x1 + r22 * x2 + g2);
    rb[0] += w * r00; rb[1] += w * r10; rb[2] += w * r20;
    rb[3] += w * r01; rb[4] += w * r11; rb[5] += w * r21;
    rb[6] += w * r02; rb[7] += w * r12; rb[8] += w * r22;
  }

  wsum += __shfl_xor(wsum, 32);
  pb0  += __shfl_xor(pb0, 32);
  pb1  += __shfl_xor(pb1, 32);
  pb2  += __shfl_xor(pb2, 32);
#pragma unroll
  for (int a2i = 0; a2i < 9; ++a2i) rb[a2i] += __shfl_xor(rb[a2i], 32);

  if (h == 0) {
    const float inw = 1.0f / wsum;
    float o0 = pb0 * inw;
    if (dmn > 0.00021f) o0 = 1000000000.0f;
    float* po = out + (size_t)gi * 3;
    po[0] = o0; po[1] = pb1 * inw; po[2] = pb2 * inw;
    float* ro = out + (size_t)NPTS * 3 + (size_t)gi * 9;
#pragma unroll
    for (int a2i = 0; a2i < 9; ++a2i) ro[a2i] = rb[a2i] * inw;
  }
}

// ---- fallback: R2-style scalar kernel (proven), if ws too small ----
__global__ __launch_bounds__(256, 4) void dg_fb(
    const float* __restrict__ inp, const float* __restrict__ vd,
    const float* __restrict__ Rm, const float* __restrict__ gv,
    const float* __restrict__ tv, float* __restrict__ out)
{
  __shared__ uint32_t st[33 * 256];
  const int tid = threadIdx.x;
  const int q   = (tid >> 4) & 3;
  const int pl  = tid & 15;
  const int wv  = tid >> 6;
  const int gi  = blockIdx.x * 64 + wv * 16 + pl;
  const float p0 = inp[gi * 35 + 0];
  const float p1 = inp[gi * 35 + 1];
  const float p2 = inp[gi * 35 + 2];
  const float sp = p0 * p0 + p1 * p1 + p2 * p2;
  uint32_t m[KSEL];
#pragma unroll
  for (int k = 0; k < KSEL; ++k) m[k] = 0xFFFFFFFFu;
  int cnt = 0;
  float thr = __uint_as_float(0x7F7FFFFFu);
  const int jbase = q * (NNODES / 4);
  int lo = 0;
#pragma unroll
  for (int c = 0; c < 6; ++c) {
    const int hi = 32 << c;
    for (int i = lo; i < hi; ++i) {
      const int j = jbase + i;
      const float v0 = vd[j * 3 + 0], v1 = vd[j * 3 + 1], v2 = vd[j * 3 + 2];
      const float sv = v0 * v0 + v1 * v1 + v2 * v2;
      const float dt = p0 * v0 + p1 * v1 + p2 * v2;
      float d2 = fmaxf((sp + sv) - 2.0f * dt, 0.0f);
      if (d2 < thr) {
        st[cnt * 256 + tid] = ((__float_as_uint(d2) & 0xFFFFF800u) << 1) | (uint32_t)j;
        if (++cnt == 33) {
          for (int u = 0; u < cnt; ++u) {
            const uint32_t x = st[u * 256 + tid];
            if (x < m[KSEL - 1]) insert20(m, x);
          }
          cnt = 0; thr = thr_from(m[KSEL - 1]);
        }
      }
    }
    for (int u = 0; u < cnt; ++u) {
      const uint32_t x = st[u * 256 + tid];
      if (x < m[KSEL - 1]) insert20(m, x);
    }
    cnt = 0; thr = thr_from(m[KSEL - 1]); lo = hi;
  }
  uint32_t arr[32];
#pragma unroll
  for (int k = 0; k < KSEL; ++k) arr[k] = m[k];
#pragma unroll
  for (int k = KSEL; k < 32; ++k) arr[k] = 0xFFFFFFFFu;
#pragma unroll
  for (int mask = 32; mask >= 16; mask >>= 1) {
#pragma unroll
    for (int k = 0; k < 16; ++k) {
      const uint32_t sa = (uint32_t)__shfl_xor((int)arr[k],      mask);
      const uint32_t sb = (uint32_t)__shfl_xor((int)arr[31 - k], mask);
      arr[k]      = umin32(arr[k],      sb);
      arr[31 - k] = umin32(arr[31 - k], sa);
    }
#pragma unroll
    for (int dd = 16; dd >= 1; dd >>= 1)
#pragma unroll
      for (int k = 0; k < 32; ++k)
        if ((k & dd) == 0) cmpswap(arr[k], arr[k | dd]);
  }
  int id5[5]; float d5[5];
  float dmn = 1e30f, dmx = -1e30f;
#pragma unroll
  for (int s = 0; s < 5; ++s) {
    const int idk = (int)(arr[4 * s + q] & 0xFFFu);
    id5[s] = idk;
    const float v0 = vd[idk * 3 + 0], v1 = vd[idk * 3 + 1], v2 = vd[idk * 3 + 2];
    const float sv = v0 * v0 + v1 * v1 + v2 * v2;
    const float dt = p0 * v0 + p1 * v1 + p2 * v2;
    const float ddx = (sp + sv) - 2.0f * dt;
    d5[s] = ddx; dmn = fminf(dmn, ddx); dmx = fmaxf(dmx, ddx);
  }
#pragma unroll
  for (int r = 16; r <= 32; r <<= 1) {
    dmx = fmaxf(dmx, __shfl_xor(dmx, r));
    dmn = fminf(dmn, __shfl_xor(dmn, r));
  }
  const float invmax = 1.0f / dmx;
  float wsum = 0.0f, pb0 = 0.0f, pb1 = 0.0f, pb2 = 0.0f;
  float rb[9];
#pragma unroll
  for (int a2i = 0; a2i < 9; ++a2i) rb[a2i] = 0.0f;
#pragma unroll
  for (int s = 0; s < 5; ++s) {
    const int idk = id5[s];
    const float u = 1.0f - d5[s] * invmax;
    const float w = u * u;
    wsum += w;
    const float* Rp = Rm + idk * 9;
    const float r00 = Rp[0], r01 = Rp[1], r02 = Rp[2];
    const float r10 = Rp[3], r11 = Rp[4], r12 = Rp[5];
    const float r20 = Rp[6], r21 = Rp[7], r22 = Rp[8];
    const float g0 = gv[idk * 3 + 0], g1 = gv[idk * 3 + 1], g2 = gv[idk * 3 + 2];
    const float t0 = tv[idk * 3 + 0], t1 = tv[idk * 3 + 1], t2 = tv[idk * 3 + 2];
    const float x0 = p0 - g0 - t0, x1 = p1 - g1 - t1, x2 = p2 - g2 - t2;
    pb0 += w * (r00 * x0 + r10 * x1 + r20 * x2 + g0);
    pb1 += w * (r01 * x0 + r11 * x1 + r21 * x2 + g1);
    pb2 += w * (r02 * x0 + r12 * x1 + r22 * x2 + g2);
    rb[0] += w * r00; rb[1] += w * r10; rb[2] += w * r20;
    rb[3] += w * r01; rb[4] += w * r11; rb[5] += w * r21;
    rb[6] += w * r02; rb[7] += w * r12; rb[8] += w * r22;
  }
#pragma unroll
  for (int r = 16; r <= 32; r <<= 1) {
    wsum += __shfl_xor(wsum, r);
    pb0 += __shfl_xor(pb0, r);
    pb1 += __shfl_xor(pb1, r);
    pb2 += __shfl_xor(pb2, r);
#pragma unroll
    for (int a2i = 0; a2i < 9; ++a2i) rb[a2i] += __shfl_xor(rb[a2i], r);
  }
  if (q == 0) {
    const float inw = 1.0f / wsum;
    float o0 = pb0 * inw;
    if (dmn > 0.00021f) o0 = 1000000000.0f;
    float* po = out + (size_t)gi * 3;
    po[0] = o0; po[1] = pb1 * inw; po[2] = pb2 * inw;
    float* ro = out + (size_t)NPTS * 3 + (size_t)gi * 9;
#pragma unroll
    for (int a2i = 0; a2i < 9; ++a2i) ro[a2i] = rb[a2i] * inw;
  }
}

extern "C" void kernel_launch(void* const* d_in, const int* in_sizes, int n_in,
                              void* d_out, int out_size, void* d_ws, size_t ws_size,
                              hipStream_t stream) {
  const float* inp = (const float*)d_in[0];
  const float* vd  = (const float*)d_in[1];
  const float* Rm  = (const float*)d_in[2];
  const float* gv  = (const float*)d_in[3];
  const float* tv  = (const float*)d_in[4];
  float* out = (float*)d_out;

  if (ws_size >= (size_t)WS_NEEDED) {
    unsigned short* aF = (unsigned short*)d_ws;
    dg_prep<<<NNODES / 256, 256, 0, stream>>>(vd, aF);
    dg_mfma<<<NPTS / 64, BT, 0, stream>>>(inp, vd, Rm, gv, tv,
                                          (const short8*)aF, out);
  } else {
    dg_fb<<<NPTS / 64, 256, 0, stream>>>(inp, vd, Rm, gv, tv, out);
  }
}